// Round 5
// baseline (443.858 us; speedup 1.0000x reference)
//
#include <hip/hip_runtime.h>
#include <hip/hip_bf16.h>

#define QN 150
#define CN 512
#define HWN 441
#define WAYN 5
#define SHOTN 5
#define NSAMP 2205           // SHOT*HW
#define MROWS (QN * HWN)     // 66150 packed rows
#define MT256 259            // ceil(66150/256)
#define MPAD2 (MT256 * 256)  // 66304
#define KP 2208              // cov K padded (32*69)
#define KPB (KP * 2)         // row bytes of x2c
#define NKCH 16              // K chunks of 32 in gemm (CN/32)

typedef unsigned short u16;
typedef unsigned int u32;
typedef __attribute__((ext_vector_type(8))) short short8;
typedef __attribute__((ext_vector_type(4))) float f32x4;

__device__ __forceinline__ u16 f2b(float f) {
    return __builtin_bit_cast(u16, __float2bfloat16(f));
}
__device__ __forceinline__ float b2f(u16 h) {
    u32 u = ((u32)h) << 16;
    return __builtin_bit_cast(float, u);
}

__device__ __forceinline__ void gload16(const void* g, void* l) {
    __builtin_amdgcn_global_load_lds(
        (const __attribute__((address_space(1))) unsigned int*)g,
        (__attribute__((address_space(3))) unsigned int*)l, 16, 0, 0);
}

// ---------------- per-(way,channel) mean over 2205 samples ----------------
__global__ void wmean_kernel(const float* __restrict__ x2, float* __restrict__ wmean) {
    int wc = blockIdx.x;            // w*512 + c
    int w = wc >> 9, c = wc & 511;
    int lane = threadIdx.x;         // 64
    float s = 0.f;
    for (int sh = 0; sh < SHOTN; ++sh) {
        const float* p = x2 + ((size_t)((w * SHOTN + sh) * CN + c)) * HWN;
        for (int i = lane; i < HWN; i += 64) s += p[i];
    }
    #pragma unroll
    for (int off = 32; off > 0; off >>= 1) s += __shfl_down(s, off);
    if (lane == 0) wmean[wc] = s * (1.0f / NSAMP);
}

// ---------------- center x2 -> bf16 x2c[w][c][k], k = s*441+pos, pad [2205,2208)=0 ----------------
__global__ void x2center_kernel(const float* __restrict__ x2,
                                const float* __restrict__ wmean,
                                u16* __restrict__ x2c) {
    int b = blockIdx.x;             // ws*512 + c
    int ws = b >> 9, c = b & 511;
    int w = ws / SHOTN, s = ws - w * SHOTN;
    int lane = threadIdx.x;
    float m = wmean[w * CN + c];
    const float* src = x2 + (size_t)b * HWN;
    u16* dst = x2c + ((size_t)(w * CN + c)) * KP + s * HWN;
    for (int i = lane; i < HWN; i += 64) dst[i] = f2b(src[i] - m);
    if (s == 0 && lane < (KP - NSAMP))
        x2c[((size_t)(w * CN + c)) * KP + NSAMP + lane] = 0;
}

// ---------------- cov MFMA: covb[w] = Xc Xc^T / (n-1), 128x128 tile, K=2208 ----------------
__global__ __launch_bounds__(256, 2) void covmfma_kernel(const u16* __restrict__ x2c,
                                                         u16* __restrict__ covb) {
    __shared__ __align__(16) u16 As[2][128 * 32];
    __shared__ __align__(16) u16 Bs[2][128 * 32];
    int w  = blockIdx.z;
    int c0 = blockIdx.y * 128;
    int d0 = blockIdx.x * 128;
    int t = threadIdx.x;
    int lane = t & 63, wid = t >> 6;
    int wr = wid >> 1, wc = wid & 1;
    int rl = lane & 15, g4 = lane >> 4;
    int swz = ((rl >> 1) & 3) << 4;
    int s0 = wid * 2048 + lane * 16;

    const char* gX = (const char*)(x2c + (size_t)w * CN * KP);

    f32x4 acc[4][4];
    #pragma unroll
    for (int mi = 0; mi < 4; ++mi)
        #pragma unroll
        for (int ni = 0; ni < 4; ++ni)
            acc[mi][ni] = (f32x4){0.f, 0.f, 0.f, 0.f};

    int buf = 0;
    #pragma unroll
    for (int j = 0; j < 2; ++j) {
        int s = s0 + j * 1024;
        int row = s >> 6, kbs = (s & 63) ^ (((row >> 1) & 3) << 4);
        gload16(gX + (size_t)(c0 + row) * KPB + kbs, (char*)&As[0][0] + wid * 2048 + j * 1024);
        gload16(gX + (size_t)(d0 + row) * KPB + kbs, (char*)&Bs[0][0] + wid * 2048 + j * 1024);
    }
    __syncthreads();

    for (int ks = 0; ks < KP / 32; ++ks) {
        if (ks < KP / 32 - 1) {
            int koff = (ks + 1) * 64;
            #pragma unroll
            for (int j = 0; j < 2; ++j) {
                int s = s0 + j * 1024;
                int row = s >> 6, kbs = (s & 63) ^ (((row >> 1) & 3) << 4);
                gload16(gX + (size_t)(c0 + row) * KPB + koff + kbs,
                        (char*)&As[buf ^ 1][0] + wid * 2048 + j * 1024);
                gload16(gX + (size_t)(d0 + row) * KPB + koff + kbs,
                        (char*)&Bs[buf ^ 1][0] + wid * 2048 + j * 1024);
            }
        }
        const char* Ab = (const char*)&As[buf][0];
        const char* Bb = (const char*)&Bs[buf][0];
        int kread = (g4 * 16) ^ swz;
        short8 a[4], b[4];
        #pragma unroll
        for (int mi = 0; mi < 4; ++mi)
            a[mi] = *(const short8*)(Ab + (wr * 64 + mi * 16 + rl) * 64 + kread);
        #pragma unroll
        for (int ni = 0; ni < 4; ++ni)
            b[ni] = *(const short8*)(Bb + (wc * 64 + ni * 16 + rl) * 64 + kread);
        #pragma unroll
        for (int mi = 0; mi < 4; ++mi)
            #pragma unroll
            for (int ni = 0; ni < 4; ++ni)
                acc[mi][ni] = __builtin_amdgcn_mfma_f32_16x16x32_bf16(
                    a[mi], b[ni], acc[mi][ni], 0, 0, 0);
        __syncthreads();
        buf ^= 1;
    }

    const float inv = 1.0f / (NSAMP - 1);
    #pragma unroll
    for (int mi = 0; mi < 4; ++mi)
        #pragma unroll
        for (int r = 0; r < 4; ++r) {
            int c = c0 + wr * 64 + mi * 16 + g4 * 4 + r;
            #pragma unroll
            for (int ni = 0; ni < 4; ++ni) {
                int d = d0 + wc * 64 + ni * 16 + rl;
                covb[((size_t)w * CN + c) * CN + d] = f2b(acc[mi][ni][r] * inv);
            }
        }
}

// ---------------- transpose+center x1 -> Abf[(q*441+i)][c] bf16 (packed rows) ----------------
__global__ __launch_bounds__(256) void qtrans_kernel(const float* __restrict__ x1,
                                                     u16* __restrict__ Abf) {
    __shared__ u16 S[512][72];
    __shared__ float qm[64];
    int c0 = blockIdx.x * 64;
    int q  = blockIdx.y;
    int t = threadIdx.x;
    int lane = t & 63, cq = t >> 6;

    for (int cc = cq; cc < 64; cc += 4) {
        int c = c0 + cc;
        const float* p = x1 + ((size_t)q * CN + c) * HWN;
        float s = 0.f;
        for (int ic = 0; ic < 8; ++ic) {
            int i = ic * 64 + lane;
            float v = (i < HWN) ? p[i] : 0.f;
            s += v;
            S[i][cc] = f2b(v);
        }
        #pragma unroll
        for (int off = 32; off > 0; off >>= 1) s += __shfl_down(s, off);
        if (lane == 0) qm[cc] = s * (1.0f / HWN);
    }
    __syncthreads();

    int coct = t & 7;
    for (int p = 0; p < 16; ++p) {
        int il = p * 32 + (t >> 3);
        if (il >= HWN) continue;
        short8 v = *(const short8*)(&S[il][coct * 8]);
        short8 o;
        #pragma unroll
        for (int j = 0; j < 8; ++j) {
            float f = b2f((u16)v[j]) - qm[coct * 8 + j];
            o[j] = (short)f2b(f);
        }
        *(short8*)(Abf + ((size_t)(q * HWN + il)) * CN + c0 + coct * 8) = o;
    }
}

// ---------------- init: zero simws + Abf pad rows ----------------
__global__ void init2_kernel(float* __restrict__ simws, u32* __restrict__ AbfPad32) {
    int tid = blockIdx.x * blockDim.x + threadIdx.x;
    int stride = gridDim.x * blockDim.x;
    int nsim = WAYN * MPAD2;
    for (int i = tid; i < nsim; i += stride) simws[i] = 0.f;
    int npadw = (MPAD2 - MROWS) * CN / 2;     // 154*512/2 u32 words
    for (int i = tid; i < npadw; i += stride) AbfPad32[i] = 0;
}

// ---------------- main: 256x256 tile, ring-4 LDS, counted vmcnt (T3+T4+T5) ----------------
// 512 thr = 8 waves (2M x 4N), wave out 128x64, BK=32, K=512 -> 16 chunks.
// LDS: A ring 4x16KB @0, B ring 4x16KB @65536 (128 KiB dynamic).
__global__ __launch_bounds__(512, 2) void gemm256_kernel(const u16* __restrict__ Abf,
                                                         const u16* __restrict__ covb,
                                                         float* __restrict__ simws) {
    extern __shared__ char smem[];

    int bx = blockIdx.x;
    int m  = bx / 10;
    int rr = bx - m * 10;           // (n,w) innermost: 10 blocks share the A m-tile
    int w  = rr % 5;
    int n0 = (rr / 5) * 256;
    int r0 = m * 256;

    int t = threadIdx.x;
    int lane = t & 63, wid = t >> 6;
    int wr = wid >> 2, wc = wid & 3;        // 2M x 4N waves
    int rl = lane & 15, g4 = lane >> 4;
    int swz = ((rl >> 1) & 3) << 4;

    const char* gA = (const char*)(Abf + (size_t)r0 * CN);      // row stride 1024 B
    const char* gB = (const char*)(covb + (size_t)w * CN * CN); // row stride 1024 B

    f32x4 acc[8][4];
    #pragma unroll
    for (int mi = 0; mi < 8; ++mi)
        #pragma unroll
        for (int ni = 0; ni < 4; ++ni)
            acc[mi][ni] = (f32x4){0.f, 0.f, 0.f, 0.f};

    // stage chunk kc (A 16KB + B 16KB) into ring slot kc&3; 4 gload16/thread
    auto stage_chunk = [&](int kc) {
        int slot = kc & 3;
        int kbyte = kc * 64;
        #pragma unroll
        for (int j = 0; j < 2; ++j) {
            int off = j * 8192 + t * 16;
            int row = off >> 6;
            int kb  = off & 63;
            int kbs = kb ^ (((row >> 1) & 3) << 4);
            char* dstA = smem + slot * 16384 + j * 8192 + wid * 1024 + lane * 16;
            char* dstB = smem + 65536 + slot * 16384 + j * 8192 + wid * 1024 + lane * 16;
            gload16(gA + (size_t)row * 1024 + kbyte + kbs, dstA);
            gload16(gB + (size_t)(n0 + row) * 1024 + kbyte + kbs, dstB);
        }
    };

    // compute chunk ks: ds_read frags, drain lgkm, barrier (slot now reusable), MFMA
    auto compute_chunk = [&](int ks) {
        const char* Ab = smem + (ks & 3) * 16384;
        const char* Bb = smem + 65536 + (ks & 3) * 16384;
        int kread = (g4 * 16) ^ swz;
        short8 a[8], b[4];
        #pragma unroll
        for (int mi = 0; mi < 8; ++mi)
            a[mi] = *(const short8*)(Ab + (wr * 128 + mi * 16 + rl) * 64 + kread);
        #pragma unroll
        for (int ni = 0; ni < 4; ++ni)
            b[ni] = *(const short8*)(Bb + (wc * 64 + ni * 16 + rl) * 64 + kread);
        asm volatile("s_waitcnt lgkmcnt(0)" ::: "memory");
        __builtin_amdgcn_s_barrier();
        __builtin_amdgcn_s_setprio(1);
        #pragma unroll
        for (int mi = 0; mi < 8; ++mi)
            #pragma unroll
            for (int ni = 0; ni < 4; ++ni)
                acc[mi][ni] = __builtin_amdgcn_mfma_f32_16x16x32_bf16(
                    a[mi], b[ni], acc[mi][ni], 0, 0, 0);
        __builtin_amdgcn_s_setprio(0);
    };

    // prologue: 3 chunks in flight
    stage_chunk(0);
    stage_chunk(1);
    stage_chunk(2);

    for (int ks = 0; ks < NKCH - 3; ++ks) {
        stage_chunk(ks + 3);
        asm volatile("s_waitcnt vmcnt(12)" ::: "memory");  // chunk ks landed; 3 in flight
        __builtin_amdgcn_s_barrier();
        compute_chunk(ks);
    }
    asm volatile("s_waitcnt vmcnt(8)" ::: "memory");
    __builtin_amdgcn_s_barrier();
    compute_chunk(NKCH - 3);
    asm volatile("s_waitcnt vmcnt(4)" ::: "memory");
    __builtin_amdgcn_s_barrier();
    compute_chunk(NKCH - 2);
    asm volatile("s_waitcnt vmcnt(0)" ::: "memory");
    __builtin_amdgcn_s_barrier();
    compute_chunk(NKCH - 1);

    // epilogue: partial sim over this block's 256 d-columns
    __syncthreads();
    float* simpart = (float*)smem;      // [256][4]
    #pragma unroll
    for (int mi = 0; mi < 8; ++mi) {
        #pragma unroll
        for (int r = 0; r < 4; ++r) {
            int Rl = wr * 128 + mi * 16 + g4 * 4 + r;
            size_t Rg = (size_t)r0 + Rl;
            float s = 0.f;
            #pragma unroll
            for (int ni = 0; ni < 4; ++ni) {
                int d = n0 + wc * 64 + ni * 16 + rl;
                s += acc[mi][ni][r] * b2f(Abf[Rg * CN + d]);
            }
            s += __shfl_xor(s, 1);
            s += __shfl_xor(s, 2);
            s += __shfl_xor(s, 4);
            s += __shfl_xor(s, 8);
            if (rl == 0) simpart[Rl * 4 + wc] = s;
        }
    }
    __syncthreads();
    if (t < 256) {
        float v = simpart[t * 4 + 0] + simpart[t * 4 + 1] +
                  simpart[t * 4 + 2] + simpart[t * 4 + 3];
        atomicAdd(&simws[(size_t)w * MPAD2 + r0 + t], v);
    }
}

// ---------------- finish: act + conv dot + bias -> scores ----------------
__global__ void finish_kernel(const float* __restrict__ simws,
                              const float* __restrict__ conv_w,
                              const float* __restrict__ conv_b,
                              float* __restrict__ scores) {
    int q = blockIdx.x, w = blockIdx.y;
    int t = threadIdx.x;    // 128
    const float* sp = simws + (size_t)w * MPAD2 + q * HWN;
    float s = 0.f;
    for (int i = t; i < HWN; i += 128) {
        float v = sp[i];
        float a = (v >= 0.f) ? v : 0.2f * v;
        s += a * conv_w[i];
    }
    __shared__ float red[2];
    #pragma unroll
    for (int off = 32; off > 0; off >>= 1) s += __shfl_down(s, off);
    if ((t & 63) == 0) red[t >> 6] = s;
    __syncthreads();
    if (t == 0) scores[q * WAYN + w] = red[0] + red[1] + conv_b[0];
}

extern "C" void kernel_launch(void* const* d_in, const int* in_sizes, int n_in,
                              void* d_out, int out_size, void* d_ws, size_t ws_size,
                              hipStream_t stream) {
    const float* x1     = (const float*)d_in[0];
    const float* x2     = (const float*)d_in[1];
    const float* conv_w = (const float*)d_in[2];
    const float* conv_b = (const float*)d_in[3];
    float* scores = (float*)d_out;

    char* ws = (char*)d_ws;
    u16* covb    = (u16*)ws;                               // 2,621,440 B
    float* wmean = (float*)(ws + 2621440);                 // 10,240 B
    float* simws = (float*)(ws + 2631680);                 // 5*66304*4 = 1,326,080 B
    // x2c aliases head of Abf (covmfma reads x2c before qtrans writes Abf)
    u16* x2c     = (u16*)(ws + 3957760);                   // 11,304,960 B
    u16* Abf     = (u16*)(ws + 3957760);                   // 66304*512*2 = 67,895,296 B

    wmean_kernel<<<WAYN * CN, 64, 0, stream>>>(x2, wmean);
    x2center_kernel<<<WAYN * SHOTN * CN, 64, 0, stream>>>(x2, wmean, x2c);
    covmfma_kernel<<<dim3(4, 4, WAYN), 256, 0, stream>>>(x2c, covb);
    qtrans_kernel<<<dim3(8, QN), 256, 0, stream>>>(x1, Abf);
    init2_kernel<<<256, 256, 0, stream>>>(simws, (u32*)(Abf + (size_t)MROWS * CN));
    gemm256_kernel<<<MT256 * 10, 512, 131072, stream>>>(Abf, covb, simws);
    finish_kernel<<<dim3(QN, WAYN), 128, 0, stream>>>(simws, conv_w, conv_b, scores);
}

// Round 6
// 373.472 us; speedup vs baseline: 1.1885x; 1.1885x over previous
//
#include <hip/hip_runtime.h>
#include <hip/hip_bf16.h>

#define QN 150
#define CN 512
#define HWN 441
#define WAYN 5
#define SHOTN 5
#define NSAMP 2205           // SHOT*HW
#define MROWS (QN * HWN)     // 66150 packed rows
#define MT256 259            // ceil(66150/256)
#define MPAD2 (MT256 * 256)  // 66304
#define KP 2208              // cov K padded (32*69)
#define KPB (KP * 2)         // row bytes of x2c
#define NKCH 16              // K chunks of 32 in gemm (CN/32)

typedef unsigned short u16;
typedef unsigned int u32;
typedef __attribute__((ext_vector_type(8))) short short8;
typedef __attribute__((ext_vector_type(4))) float f32x4;

__device__ __forceinline__ u16 f2b(float f) {
    return __builtin_bit_cast(u16, __float2bfloat16(f));
}
__device__ __forceinline__ float b2f(u16 h) {
    u32 u = ((u32)h) << 16;
    return __builtin_bit_cast(float, u);
}

__device__ __forceinline__ void gload16(const void* g, void* l) {
    __builtin_amdgcn_global_load_lds(
        (const __attribute__((address_space(1))) unsigned int*)g,
        (__attribute__((address_space(3))) unsigned int*)l, 16, 0, 0);
}

// ---------------- per-(way,channel) mean over 2205 samples ----------------
__global__ void wmean_kernel(const float* __restrict__ x2, float* __restrict__ wmean) {
    int wc = blockIdx.x;            // w*512 + c
    int w = wc >> 9, c = wc & 511;
    int lane = threadIdx.x;         // 64
    float s = 0.f;
    for (int sh = 0; sh < SHOTN; ++sh) {
        const float* p = x2 + ((size_t)((w * SHOTN + sh) * CN + c)) * HWN;
        for (int i = lane; i < HWN; i += 64) s += p[i];
    }
    #pragma unroll
    for (int off = 32; off > 0; off >>= 1) s += __shfl_down(s, off);
    if (lane == 0) wmean[wc] = s * (1.0f / NSAMP);
}

// ---------------- center x2 -> bf16 x2c[w][c][k], k = s*441+pos, pad [2205,2208)=0 ----------------
__global__ void x2center_kernel(const float* __restrict__ x2,
                                const float* __restrict__ wmean,
                                u16* __restrict__ x2c) {
    int b = blockIdx.x;             // ws*512 + c
    int ws = b >> 9, c = b & 511;
    int w = ws / SHOTN, s = ws - w * SHOTN;
    int lane = threadIdx.x;
    float m = wmean[w * CN + c];
    const float* src = x2 + (size_t)b * HWN;
    u16* dst = x2c + ((size_t)(w * CN + c)) * KP + s * HWN;
    for (int i = lane; i < HWN; i += 64) dst[i] = f2b(src[i] - m);
    if (s == 0 && lane < (KP - NSAMP))
        x2c[((size_t)(w * CN + c)) * KP + NSAMP + lane] = 0;
}

// ---------------- cov MFMA: covb[w] = Xc Xc^T / (n-1), 128x128 tile, K=2208 ----------------
__global__ __launch_bounds__(256, 2) void covmfma_kernel(const u16* __restrict__ x2c,
                                                         u16* __restrict__ covb) {
    __shared__ __align__(16) u16 As[2][128 * 32];
    __shared__ __align__(16) u16 Bs[2][128 * 32];
    int w  = blockIdx.z;
    int c0 = blockIdx.y * 128;
    int d0 = blockIdx.x * 128;
    int t = threadIdx.x;
    int lane = t & 63, wid = t >> 6;
    int wr = wid >> 1, wc = wid & 1;
    int rl = lane & 15, g4 = lane >> 4;
    int swz = ((rl >> 1) & 3) << 4;
    int s0 = wid * 2048 + lane * 16;

    const char* gX = (const char*)(x2c + (size_t)w * CN * KP);

    f32x4 acc[4][4];
    #pragma unroll
    for (int mi = 0; mi < 4; ++mi)
        #pragma unroll
        for (int ni = 0; ni < 4; ++ni)
            acc[mi][ni] = (f32x4){0.f, 0.f, 0.f, 0.f};

    int buf = 0;
    #pragma unroll
    for (int j = 0; j < 2; ++j) {
        int s = s0 + j * 1024;
        int row = s >> 6, kbs = (s & 63) ^ (((row >> 1) & 3) << 4);
        gload16(gX + (size_t)(c0 + row) * KPB + kbs, (char*)&As[0][0] + wid * 2048 + j * 1024);
        gload16(gX + (size_t)(d0 + row) * KPB + kbs, (char*)&Bs[0][0] + wid * 2048 + j * 1024);
    }
    __syncthreads();

    for (int ks = 0; ks < KP / 32; ++ks) {
        if (ks < KP / 32 - 1) {
            int koff = (ks + 1) * 64;
            #pragma unroll
            for (int j = 0; j < 2; ++j) {
                int s = s0 + j * 1024;
                int row = s >> 6, kbs = (s & 63) ^ (((row >> 1) & 3) << 4);
                gload16(gX + (size_t)(c0 + row) * KPB + koff + kbs,
                        (char*)&As[buf ^ 1][0] + wid * 2048 + j * 1024);
                gload16(gX + (size_t)(d0 + row) * KPB + koff + kbs,
                        (char*)&Bs[buf ^ 1][0] + wid * 2048 + j * 1024);
            }
        }
        const char* Ab = (const char*)&As[buf][0];
        const char* Bb = (const char*)&Bs[buf][0];
        int kread = (g4 * 16) ^ swz;
        short8 a[4], b[4];
        #pragma unroll
        for (int mi = 0; mi < 4; ++mi)
            a[mi] = *(const short8*)(Ab + (wr * 64 + mi * 16 + rl) * 64 + kread);
        #pragma unroll
        for (int ni = 0; ni < 4; ++ni)
            b[ni] = *(const short8*)(Bb + (wc * 64 + ni * 16 + rl) * 64 + kread);
        #pragma unroll
        for (int mi = 0; mi < 4; ++mi)
            #pragma unroll
            for (int ni = 0; ni < 4; ++ni)
                acc[mi][ni] = __builtin_amdgcn_mfma_f32_16x16x32_bf16(
                    a[mi], b[ni], acc[mi][ni], 0, 0, 0);
        __syncthreads();
        buf ^= 1;
    }

    const float inv = 1.0f / (NSAMP - 1);
    #pragma unroll
    for (int mi = 0; mi < 4; ++mi)
        #pragma unroll
        for (int r = 0; r < 4; ++r) {
            int c = c0 + wr * 64 + mi * 16 + g4 * 4 + r;
            #pragma unroll
            for (int ni = 0; ni < 4; ++ni) {
                int d = d0 + wc * 64 + ni * 16 + rl;
                covb[((size_t)w * CN + c) * CN + d] = f2b(acc[mi][ni][r] * inv);
            }
        }
}

// ---------------- transpose+center x1 -> Abf[(q*441+i)][c] bf16 (packed rows) ----------------
__global__ __launch_bounds__(256) void qtrans_kernel(const float* __restrict__ x1,
                                                     u16* __restrict__ Abf) {
    __shared__ u16 S[512][72];
    __shared__ float qm[64];
    int c0 = blockIdx.x * 64;
    int q  = blockIdx.y;
    int t = threadIdx.x;
    int lane = t & 63, cq = t >> 6;

    for (int cc = cq; cc < 64; cc += 4) {
        int c = c0 + cc;
        const float* p = x1 + ((size_t)q * CN + c) * HWN;
        float s = 0.f;
        for (int ic = 0; ic < 8; ++ic) {
            int i = ic * 64 + lane;
            float v = (i < HWN) ? p[i] : 0.f;
            s += v;
            S[i][cc] = f2b(v);
        }
        #pragma unroll
        for (int off = 32; off > 0; off >>= 1) s += __shfl_down(s, off);
        if (lane == 0) qm[cc] = s * (1.0f / HWN);
    }
    __syncthreads();

    int coct = t & 7;
    for (int p = 0; p < 16; ++p) {
        int il = p * 32 + (t >> 3);
        if (il >= HWN) continue;
        short8 v = *(const short8*)(&S[il][coct * 8]);
        short8 o;
        #pragma unroll
        for (int j = 0; j < 8; ++j) {
            float f = b2f((u16)v[j]) - qm[coct * 8 + j];
            o[j] = (short)f2b(f);
        }
        *(short8*)(Abf + ((size_t)(q * HWN + il)) * CN + c0 + coct * 8) = o;
    }
}

// ---------------- init: zero simws + Abf pad rows ----------------
__global__ void init2_kernel(float* __restrict__ simws, u32* __restrict__ AbfPad32) {
    int tid = blockIdx.x * blockDim.x + threadIdx.x;
    int stride = gridDim.x * blockDim.x;
    int nsim = WAYN * MPAD2;
    for (int i = tid; i < nsim; i += stride) simws[i] = 0.f;
    int npadw = (MPAD2 - MROWS) * CN / 2;
    for (int i = tid; i < npadw; i += stride) AbfPad32[i] = 0;
}

// ---------------- main: 256x256 tile, ring-4 LDS, fine 2-phase/chunk interleave ----------------
// 512 thr = 8 waves (2M x 4N), wave out 128x64, chunk K=32, K=512 -> 16 chunks.
// LDS: A ring 4x16KB @0, B ring 4x16KB @65536 (128 KiB dynamic).
// XCD co-location: bid%8 = XCD; 10 blocks of one A m-tile share an XCD's L2.
__global__ __launch_bounds__(512, 2) void gemm256_kernel(const u16* __restrict__ Abf,
                                                         const u16* __restrict__ covb,
                                                         float* __restrict__ simws) {
    extern __shared__ char smem[];

    int x = blockIdx.x & 7;
    int l = blockIdx.x >> 3;
    int m = x * 33 + l / 10;
    if (m >= MT256) return;
    int nw = l - (l / 10) * 10;
    int w  = nw % 5;
    int n0 = (nw / 5) * 256;
    int r0 = m * 256;

    int t = threadIdx.x;
    int lane = t & 63, wid = t >> 6;
    int wr = wid >> 2, wc = wid & 3;        // 2M x 4N waves
    int rl = lane & 15, g4 = lane >> 4;
    int swz = ((rl >> 1) & 3) << 4;

    const char* gA = (const char*)(Abf + (size_t)r0 * CN);      // row stride 1024 B
    const char* gB = (const char*)(covb + (size_t)w * CN * CN); // row stride 1024 B

    f32x4 acc[8][4];
    #pragma unroll
    for (int mi = 0; mi < 8; ++mi)
        #pragma unroll
        for (int ni = 0; ni < 4; ++ni)
            acc[mi][ni] = (f32x4){0.f, 0.f, 0.f, 0.f};

    // stage half (j=0/1) of chunk kc: one A gload16 + one B gload16 per thread
    auto stage_pair = [&](int kc, int j) {
        int slot = kc & 3;
        int kbyte = kc * 64;
        int off = j * 8192 + t * 16;
        int row = off >> 6;
        int kbs = (off & 63) ^ (((row >> 1) & 3) << 4);
        gload16(gA + (size_t)row * 1024 + kbyte + kbs, smem + slot * 16384 + off);
        gload16(gB + (size_t)(n0 + row) * 1024 + kbyte + kbs,
                smem + 65536 + slot * 16384 + off);
    };

    // one chunk = 2 fine phases: {8 ds_read + 2 gload + 16 MFMA} | {4 ds_read + 2 gload + 16 MFMA}
    auto chunk = [&](int c, bool doStage) {
        const char* Ab = smem + (c & 3) * 16384;
        const char* Bb = smem + 65536 + (c & 3) * 16384;
        int kread = (g4 * 16) ^ swz;
        short8 a[8], b[4];
        // ---- phase A ----
        #pragma unroll
        for (int mi = 0; mi < 4; ++mi)
            a[mi] = *(const short8*)(Ab + (wr * 128 + mi * 16 + rl) * 64 + kread);
        #pragma unroll
        for (int ni = 0; ni < 4; ++ni)
            b[ni] = *(const short8*)(Bb + (wc * 64 + ni * 16 + rl) * 64 + kread);
        if (doStage) stage_pair(c + 3, 0);
        __builtin_amdgcn_s_setprio(1);
        #pragma unroll
        for (int mi = 0; mi < 4; ++mi)
            #pragma unroll
            for (int ni = 0; ni < 4; ++ni)
                acc[mi][ni] = __builtin_amdgcn_mfma_f32_16x16x32_bf16(
                    a[mi], b[ni], acc[mi][ni], 0, 0, 0);
        __builtin_amdgcn_s_setprio(0);
        __builtin_amdgcn_s_barrier();
        asm volatile("" ::: "memory");
        // ---- phase B ----
        #pragma unroll
        for (int mi = 4; mi < 8; ++mi)
            a[mi] = *(const short8*)(Ab + (wr * 128 + mi * 16 + rl) * 64 + kread);
        if (doStage) stage_pair(c + 3, 1);
        __builtin_amdgcn_s_setprio(1);
        #pragma unroll
        for (int mi = 4; mi < 8; ++mi)
            #pragma unroll
            for (int ni = 0; ni < 4; ++ni)
                acc[mi][ni] = __builtin_amdgcn_mfma_f32_16x16x32_bf16(
                    a[mi], b[ni], acc[mi][ni], 0, 0, 0);
        __builtin_amdgcn_s_setprio(0);
    };

    // prologue: 3 chunks in flight (12 loads/thread)
    stage_pair(0, 0); stage_pair(0, 1);
    stage_pair(1, 0); stage_pair(1, 1);
    stage_pair(2, 0); stage_pair(2, 1);

    for (int c = 0; c <= 12; ++c) {
        asm volatile("s_waitcnt vmcnt(8)" ::: "memory");   // chunk c landed (own wave)
        __builtin_amdgcn_s_barrier();                      // all waves' chunk c landed
        asm volatile("" ::: "memory");
        chunk(c, true);
        __builtin_amdgcn_s_barrier();
        asm volatile("" ::: "memory");
    }
    asm volatile("s_waitcnt vmcnt(8)" ::: "memory");
    __builtin_amdgcn_s_barrier();
    asm volatile("" ::: "memory");
    chunk(13, false);
    __builtin_amdgcn_s_barrier();
    asm volatile("" ::: "memory");
    asm volatile("s_waitcnt vmcnt(4)" ::: "memory");
    __builtin_amdgcn_s_barrier();
    asm volatile("" ::: "memory");
    chunk(14, false);
    __builtin_amdgcn_s_barrier();
    asm volatile("" ::: "memory");
    asm volatile("s_waitcnt vmcnt(0)" ::: "memory");
    __builtin_amdgcn_s_barrier();
    asm volatile("" ::: "memory");
    chunk(15, false);

    // epilogue: partial sim over this block's 256 d-columns
    __syncthreads();
    float* simpart = (float*)smem;      // [256][5] stride-5 -> conflict-free
    #pragma unroll
    for (int mi = 0; mi < 8; ++mi) {
        #pragma unroll
        for (int r = 0; r < 4; ++r) {
            int Rl = wr * 128 + mi * 16 + g4 * 4 + r;
            size_t Rg = (size_t)r0 + Rl;
            float s = 0.f;
            #pragma unroll
            for (int ni = 0; ni < 4; ++ni) {
                int d = n0 + wc * 64 + ni * 16 + rl;
                s += acc[mi][ni][r] * b2f(Abf[Rg * CN + d]);
            }
            s += __shfl_xor(s, 1);
            s += __shfl_xor(s, 2);
            s += __shfl_xor(s, 4);
            s += __shfl_xor(s, 8);
            if (rl == 0) simpart[Rl * 5 + wc] = s;
        }
    }
    __syncthreads();
    if (t < 256) {
        float v = simpart[t * 5 + 0] + simpart[t * 5 + 1] +
                  simpart[t * 5 + 2] + simpart[t * 5 + 3];
        atomicAdd(&simws[(size_t)w * MPAD2 + r0 + t], v);
    }
}

// ---------------- finish: act + conv dot + bias -> scores ----------------
__global__ void finish_kernel(const float* __restrict__ simws,
                              const float* __restrict__ conv_w,
                              const float* __restrict__ conv_b,
                              float* __restrict__ scores) {
    int q = blockIdx.x, w = blockIdx.y;
    int t = threadIdx.x;    // 128
    const float* sp = simws + (size_t)w * MPAD2 + q * HWN;
    float s = 0.f;
    for (int i = t; i < HWN; i += 128) {
        float v = sp[i];
        float a = (v >= 0.f) ? v : 0.2f * v;
        s += a * conv_w[i];
    }
    __shared__ float red[2];
    #pragma unroll
    for (int off = 32; off > 0; off >>= 1) s += __shfl_down(s, off);
    if ((t & 63) == 0) red[t >> 6] = s;
    __syncthreads();
    if (t == 0) scores[q * WAYN + w] = red[0] + red[1] + conv_b[0];
}

extern "C" void kernel_launch(void* const* d_in, const int* in_sizes, int n_in,
                              void* d_out, int out_size, void* d_ws, size_t ws_size,
                              hipStream_t stream) {
    const float* x1     = (const float*)d_in[0];
    const float* x2     = (const float*)d_in[1];
    const float* conv_w = (const float*)d_in[2];
    const float* conv_b = (const float*)d_in[3];
    float* scores = (float*)d_out;

    char* ws = (char*)d_ws;
    u16* covb    = (u16*)ws;                               // 2,621,440 B
    float* wmean = (float*)(ws + 2621440);                 // 10,240 B
    float* simws = (float*)(ws + 2631680);                 // 5*66304*4 = 1,326,080 B
    // x2c aliases head of Abf (covmfma reads x2c before qtrans writes Abf)
    u16* x2c     = (u16*)(ws + 3957760);                   // 11,304,960 B
    u16* Abf     = (u16*)(ws + 3957760);                   // 66304*512*2 = 67,895,296 B

    wmean_kernel<<<WAYN * CN, 64, 0, stream>>>(x2, wmean);
    x2center_kernel<<<WAYN * SHOTN * CN, 64, 0, stream>>>(x2, wmean, x2c);
    covmfma_kernel<<<dim3(4, 4, WAYN), 256, 0, stream>>>(x2c, covb);
    qtrans_kernel<<<dim3(8, QN), 256, 0, stream>>>(x1, Abf);
    init2_kernel<<<256, 256, 0, stream>>>(simws, (u32*)(Abf + (size_t)MROWS * CN));
    gemm256_kernel<<<8 * 330, 512, 131072, stream>>>(Abf, covb, simws);
    finish_kernel<<<dim3(QN, WAYN), 128, 0, stream>>>(simws, conv_w, conv_b, scores);
}

// Round 7
// 349.509 us; speedup vs baseline: 1.2699x; 1.0686x over previous
//
#include <hip/hip_runtime.h>
#include <hip/hip_bf16.h>

#define QN 150
#define CN 512
#define HWN 441
#define WAYN 5
#define SHOTN 5
#define NSAMP 2205           // SHOT*HW
#define MROWS (QN * HWN)     // 66150 packed rows
#define MT256 259            // ceil(66150/256)
#define MPAD2 (MT256 * 256)  // 66304
#define KP 2208              // cov K padded (32*69)
#define KPB (KP * 2)         // row bytes of x2c
#define NKCH 16              // K chunks of 32 in gemm (CN/32)

typedef unsigned short u16;
typedef unsigned int u32;
typedef __attribute__((ext_vector_type(8))) short short8;
typedef __attribute__((ext_vector_type(4))) float f32x4;

__device__ __forceinline__ u16 f2b(float f) {
    return __builtin_bit_cast(u16, __float2bfloat16(f));
}
__device__ __forceinline__ float b2f(u16 h) {
    u32 u = ((u32)h) << 16;
    return __builtin_bit_cast(float, u);
}

__device__ __forceinline__ void gload16(const void* g, void* l) {
    __builtin_amdgcn_global_load_lds(
        (const __attribute__((address_space(1))) unsigned int*)g,
        (__attribute__((address_space(3))) unsigned int*)l, 16, 0, 0);
}

// ---------------- per-(way,channel) mean over 2205 samples ----------------
__global__ void wmean_kernel(const float* __restrict__ x2, float* __restrict__ wmean) {
    int wc = blockIdx.x;            // w*512 + c
    int w = wc >> 9, c = wc & 511;
    int lane = threadIdx.x;         // 64
    float s = 0.f;
    for (int sh = 0; sh < SHOTN; ++sh) {
        const float* p = x2 + ((size_t)((w * SHOTN + sh) * CN + c)) * HWN;
        for (int i = lane; i < HWN; i += 64) s += p[i];
    }
    #pragma unroll
    for (int off = 32; off > 0; off >>= 1) s += __shfl_down(s, off);
    if (lane == 0) wmean[wc] = s * (1.0f / NSAMP);
}

// ---------------- center x2 -> bf16 x2c[w][c][k], k = s*441+pos, pad [2205,2208)=0 ----------------
__global__ void x2center_kernel(const float* __restrict__ x2,
                                const float* __restrict__ wmean,
                                u16* __restrict__ x2c) {
    int b = blockIdx.x;             // ws*512 + c
    int ws = b >> 9, c = b & 511;
    int w = ws / SHOTN, s = ws - w * SHOTN;
    int lane = threadIdx.x;
    float m = wmean[w * CN + c];
    const float* src = x2 + (size_t)b * HWN;
    u16* dst = x2c + ((size_t)(w * CN + c)) * KP + s * HWN;
    for (int i = lane; i < HWN; i += 64) dst[i] = f2b(src[i] - m);
    if (s == 0 && lane < (KP - NSAMP))
        x2c[((size_t)(w * CN + c)) * KP + NSAMP + lane] = 0;
}

// ---------------- cov MFMA split-K: covf[w] += Xc[:,ks] Xc[:,ks]^T / (n-1) ----------------
// grid (4,4,15): z = w*3 + ks, each block does K=736 (23 chunks of 32)
__global__ __launch_bounds__(256, 2) void covmfma_kernel(const u16* __restrict__ x2c,
                                                         float* __restrict__ covf) {
    __shared__ __align__(16) u16 As[2][128 * 32];
    __shared__ __align__(16) u16 Bs[2][128 * 32];
    int z  = blockIdx.z;
    int w  = z / 3, ksp = z - w * 3;
    int c0 = blockIdx.y * 128;
    int d0 = blockIdx.x * 128;
    int t = threadIdx.x;
    int lane = t & 63, wid = t >> 6;
    int wr = wid >> 1, wc = wid & 1;
    int rl = lane & 15, g4 = lane >> 4;
    int swz = ((rl >> 1) & 3) << 4;
    int s0 = wid * 2048 + lane * 16;

    const char* gX = (const char*)(x2c + (size_t)w * CN * KP) + ksp * 1472; // 736 elems

    f32x4 acc[4][4];
    #pragma unroll
    for (int mi = 0; mi < 4; ++mi)
        #pragma unroll
        for (int ni = 0; ni < 4; ++ni)
            acc[mi][ni] = (f32x4){0.f, 0.f, 0.f, 0.f};

    int buf = 0;
    #pragma unroll
    for (int j = 0; j < 2; ++j) {
        int s = s0 + j * 1024;
        int row = s >> 6, kbs = (s & 63) ^ (((row >> 1) & 3) << 4);
        gload16(gX + (size_t)(c0 + row) * KPB + kbs, (char*)&As[0][0] + wid * 2048 + j * 1024);
        gload16(gX + (size_t)(d0 + row) * KPB + kbs, (char*)&Bs[0][0] + wid * 2048 + j * 1024);
    }
    __syncthreads();

    for (int ks = 0; ks < 23; ++ks) {
        if (ks < 22) {
            int koff = (ks + 1) * 64;
            #pragma unroll
            for (int j = 0; j < 2; ++j) {
                int s = s0 + j * 1024;
                int row = s >> 6, kbs = (s & 63) ^ (((row >> 1) & 3) << 4);
                gload16(gX + (size_t)(c0 + row) * KPB + koff + kbs,
                        (char*)&As[buf ^ 1][0] + wid * 2048 + j * 1024);
                gload16(gX + (size_t)(d0 + row) * KPB + koff + kbs,
                        (char*)&Bs[buf ^ 1][0] + wid * 2048 + j * 1024);
            }
        }
        const char* Ab = (const char*)&As[buf][0];
        const char* Bb = (const char*)&Bs[buf][0];
        int kread = (g4 * 16) ^ swz;
        short8 a[4], b[4];
        #pragma unroll
        for (int mi = 0; mi < 4; ++mi)
            a[mi] = *(const short8*)(Ab + (wr * 64 + mi * 16 + rl) * 64 + kread);
        #pragma unroll
        for (int ni = 0; ni < 4; ++ni)
            b[ni] = *(const short8*)(Bb + (wc * 64 + ni * 16 + rl) * 64 + kread);
        #pragma unroll
        for (int mi = 0; mi < 4; ++mi)
            #pragma unroll
            for (int ni = 0; ni < 4; ++ni)
                acc[mi][ni] = __builtin_amdgcn_mfma_f32_16x16x32_bf16(
                    a[mi], b[ni], acc[mi][ni], 0, 0, 0);
        __syncthreads();
        buf ^= 1;
    }

    const float inv = 1.0f / (NSAMP - 1);
    #pragma unroll
    for (int mi = 0; mi < 4; ++mi)
        #pragma unroll
        for (int r = 0; r < 4; ++r) {
            int c = c0 + wr * 64 + mi * 16 + g4 * 4 + r;
            #pragma unroll
            for (int ni = 0; ni < 4; ++ni) {
                int d = d0 + wc * 64 + ni * 16 + rl;
                atomicAdd(&covf[((size_t)w * CN + c) * CN + d], acc[mi][ni][r] * inv);
            }
        }
}

// ---------------- covf -> covb bf16 ----------------
__global__ void cov2b_kernel(const float* __restrict__ covf, u16* __restrict__ covb) {
    int i = blockIdx.x * 256 + threadIdx.x;
    covb[i] = f2b(covf[i]);
}

// ---------------- transpose+center x1 -> Abf[(q*441+i)][c] bf16 (packed rows) ----------------
__global__ __launch_bounds__(256) void qtrans_kernel(const float* __restrict__ x1,
                                                     u16* __restrict__ Abf) {
    __shared__ u16 S[512][72];
    __shared__ float qm[64];
    int c0 = blockIdx.x * 64;
    int q  = blockIdx.y;
    int t = threadIdx.x;
    int lane = t & 63, cq = t >> 6;

    for (int cc = cq; cc < 64; cc += 4) {
        int c = c0 + cc;
        const float* p = x1 + ((size_t)q * CN + c) * HWN;
        float s = 0.f;
        for (int ic = 0; ic < 8; ++ic) {
            int i = ic * 64 + lane;
            float v = (i < HWN) ? p[i] : 0.f;
            s += v;
            S[i][cc] = f2b(v);
        }
        #pragma unroll
        for (int off = 32; off > 0; off >>= 1) s += __shfl_down(s, off);
        if (lane == 0) qm[cc] = s * (1.0f / HWN);
    }
    __syncthreads();

    int coct = t & 7;
    for (int p = 0; p < 16; ++p) {
        int il = p * 32 + (t >> 3);
        if (il >= HWN) continue;
        short8 v = *(const short8*)(&S[il][coct * 8]);
        short8 o;
        #pragma unroll
        for (int j = 0; j < 8; ++j) {
            float f = b2f((u16)v[j]) - qm[coct * 8 + j];
            o[j] = (short)f2b(f);
        }
        *(short8*)(Abf + ((size_t)(q * HWN + il)) * CN + c0 + coct * 8) = o;
    }
}

// ---------------- init: zero simws + covf + Abf pad rows ----------------
__global__ void init2_kernel(float* __restrict__ simws, float* __restrict__ covf,
                             u32* __restrict__ AbfPad32) {
    int tid = blockIdx.x * blockDim.x + threadIdx.x;
    int stride = gridDim.x * blockDim.x;
    int nsim = WAYN * MPAD2;
    for (int i = tid; i < nsim; i += stride) simws[i] = 0.f;
    int ncov = WAYN * CN * CN;
    for (int i = tid; i < ncov; i += stride) covf[i] = 0.f;
    int npadw = (MPAD2 - MROWS) * CN / 2;
    for (int i = tid; i < npadw; i += stride) AbfPad32[i] = 0;
}

// ---------------- main: 256x256 tile, ring-4 LDS, m201-style 2-phase chunks ----------------
// 512 thr = 8 waves (2M x 4N), wave out 128x64, chunk K=32, K=512 -> 16 chunks.
// LDS: A ring 4x16KB @0, B ring 4x16KB @65536 (128 KiB dynamic).
// Phase = {ds_read burst + stage} -> lgkmcnt(0) -> sched_barrier -> MFMA x16 -> barrier.
__global__ __launch_bounds__(512, 2) void gemm256_kernel(const u16* __restrict__ Abf,
                                                         const u16* __restrict__ covb,
                                                         float* __restrict__ simws) {
    extern __shared__ char smem[];

    int x = blockIdx.x & 7;
    int l = blockIdx.x >> 3;
    int m = x * 33 + l / 10;
    if (m >= MT256) return;
    int nw = l - (l / 10) * 10;
    int w  = nw % 5;
    int n0 = (nw / 5) * 256;
    int r0 = m * 256;

    int t = threadIdx.x;
    int lane = t & 63, wid = t >> 6;
    int wr = wid >> 2, wc = wid & 3;        // 2M x 4N waves
    int rl = lane & 15, g4 = lane >> 4;
    int swz = ((rl >> 1) & 3) << 4;

    const char* gA = (const char*)(Abf + (size_t)r0 * CN);      // row stride 1024 B
    const char* gB = (const char*)(covb + (size_t)w * CN * CN); // row stride 1024 B

    f32x4 acc[8][4];
    #pragma unroll
    for (int mi = 0; mi < 8; ++mi)
        #pragma unroll
        for (int ni = 0; ni < 4; ++ni)
            acc[mi][ni] = (f32x4){0.f, 0.f, 0.f, 0.f};

    // stage half (j=0/1) of chunk kc: one A gload16 + one B gload16 per thread
    auto stage_pair = [&](int kc, int j) {
        int slot = kc & 3;
        int kbyte = kc * 64;
        int off = j * 8192 + t * 16;
        int row = off >> 6;
        int kbs = (off & 63) ^ (((row >> 1) & 3) << 4);
        gload16(gA + (size_t)row * 1024 + kbyte + kbs, smem + slot * 16384 + off);
        gload16(gB + (size_t)(n0 + row) * 1024 + kbyte + kbs,
                smem + 65536 + slot * 16384 + off);
    };

    // chunk = 2 m201-style phases; caller provides the chunk-top vmcnt+barrier
    auto do_chunk = [&](int c, bool doStage) {
        const char* Ab = smem + (c & 3) * 16384;
        const char* Bb = smem + 65536 + (c & 3) * 16384;
        int kread = (g4 * 16) ^ swz;
        short8 a[8], b[4];
        // ---- phase A: 8 ds_read + 2 gload -> drain -> 16 MFMA ----
        #pragma unroll
        for (int mi = 0; mi < 4; ++mi)
            a[mi] = *(const short8*)(Ab + (wr * 128 + mi * 16 + rl) * 64 + kread);
        #pragma unroll
        for (int ni = 0; ni < 4; ++ni)
            b[ni] = *(const short8*)(Bb + (wc * 64 + ni * 16 + rl) * 64 + kread);
        if (doStage) stage_pair(c + 3, 0);
        asm volatile("s_waitcnt lgkmcnt(0)" ::: "memory");
        __builtin_amdgcn_sched_barrier(0);
        __builtin_amdgcn_s_setprio(1);
        #pragma unroll
        for (int mi = 0; mi < 4; ++mi)
            #pragma unroll
            for (int ni = 0; ni < 4; ++ni)
                acc[mi][ni] = __builtin_amdgcn_mfma_f32_16x16x32_bf16(
                    a[mi], b[ni], acc[mi][ni], 0, 0, 0);
        __builtin_amdgcn_s_setprio(0);
        __builtin_amdgcn_s_barrier();
        asm volatile("" ::: "memory");
        // ---- phase B: 4 ds_read + 2 gload -> drain -> 16 MFMA (b reused) ----
        #pragma unroll
        for (int mi = 4; mi < 8; ++mi)
            a[mi] = *(const short8*)(Ab + (wr * 128 + mi * 16 + rl) * 64 + kread);
        if (doStage) stage_pair(c + 3, 1);
        asm volatile("s_waitcnt lgkmcnt(0)" ::: "memory");
        __builtin_amdgcn_sched_barrier(0);
        __builtin_amdgcn_s_setprio(1);
        #pragma unroll
        for (int mi = 4; mi < 8; ++mi)
            #pragma unroll
            for (int ni = 0; ni < 4; ++ni)
                acc[mi][ni] = __builtin_amdgcn_mfma_f32_16x16x32_bf16(
                    a[mi], b[ni], acc[mi][ni], 0, 0, 0);
        __builtin_amdgcn_s_setprio(0);
        // no trailing barrier: next chunk-top barrier closes this slot's reads
    };

    // prologue: 3 chunks in flight (12 loads/thread)
    stage_pair(0, 0); stage_pair(0, 1);
    stage_pair(1, 0); stage_pair(1, 1);
    stage_pair(2, 0); stage_pair(2, 1);

    #pragma unroll 1
    for (int c = 0; c < 13; ++c) {
        asm volatile("s_waitcnt vmcnt(8)" ::: "memory");   // own chunk-c loads landed
        __builtin_amdgcn_s_barrier();                      // all waves: c landed + slot c-1 reads closed
        asm volatile("" ::: "memory");
        do_chunk(c, true);
    }
    asm volatile("s_waitcnt vmcnt(8)" ::: "memory");
    __builtin_amdgcn_s_barrier();
    asm volatile("" ::: "memory");
    do_chunk(13, false);
    asm volatile("s_waitcnt vmcnt(4)" ::: "memory");
    __builtin_amdgcn_s_barrier();
    asm volatile("" ::: "memory");
    do_chunk(14, false);
    asm volatile("s_waitcnt vmcnt(0)" ::: "memory");
    __builtin_amdgcn_s_barrier();
    asm volatile("" ::: "memory");
    do_chunk(15, false);

    // epilogue: partial sim over this block's 256 d-columns
    __syncthreads();
    float* simpart = (float*)smem;      // [256][5] stride-5 -> conflict-free
    #pragma unroll
    for (int mi = 0; mi < 8; ++mi) {
        #pragma unroll
        for (int r = 0; r < 4; ++r) {
            int Rl = wr * 128 + mi * 16 + g4 * 4 + r;
            size_t Rg = (size_t)r0 + Rl;
            float s = 0.f;
            #pragma unroll
            for (int ni = 0; ni < 4; ++ni) {
                int d = n0 + wc * 64 + ni * 16 + rl;
                s += acc[mi][ni][r] * b2f(Abf[Rg * CN + d]);
            }
            s += __shfl_xor(s, 1);
            s += __shfl_xor(s, 2);
            s += __shfl_xor(s, 4);
            s += __shfl_xor(s, 8);
            if (rl == 0) simpart[Rl * 5 + wc] = s;
        }
    }
    __syncthreads();
    if (t < 256) {
        float v = simpart[t * 5 + 0] + simpart[t * 5 + 1] +
                  simpart[t * 5 + 2] + simpart[t * 5 + 3];
        atomicAdd(&simws[(size_t)w * MPAD2 + r0 + t], v);
    }
}

// ---------------- finish: act + conv dot + bias -> scores ----------------
__global__ void finish_kernel(const float* __restrict__ simws,
                              const float* __restrict__ conv_w,
                              const float* __restrict__ conv_b,
                              float* __restrict__ scores) {
    int q = blockIdx.x, w = blockIdx.y;
    int t = threadIdx.x;    // 128
    const float* sp = simws + (size_t)w * MPAD2 + q * HWN;
    float s = 0.f;
    for (int i = t; i < HWN; i += 128) {
        float v = sp[i];
        float a = (v >= 0.f) ? v : 0.2f * v;
        s += a * conv_w[i];
    }
    __shared__ float red[2];
    #pragma unroll
    for (int off = 32; off > 0; off >>= 1) s += __shfl_down(s, off);
    if ((t & 63) == 0) red[t >> 6] = s;
    __syncthreads();
    if (t == 0) scores[q * WAYN + w] = red[0] + red[1] + conv_b[0];
}

extern "C" void kernel_launch(void* const* d_in, const int* in_sizes, int n_in,
                              void* d_out, int out_size, void* d_ws, size_t ws_size,
                              hipStream_t stream) {
    const float* x1     = (const float*)d_in[0];
    const float* x2     = (const float*)d_in[1];
    const float* conv_w = (const float*)d_in[2];
    const float* conv_b = (const float*)d_in[3];
    float* scores = (float*)d_out;

    char* ws = (char*)d_ws;
    u16* covb    = (u16*)ws;                               // 2,621,440 B
    float* wmean = (float*)(ws + 2621440);                 // 10,240 B
    float* simws = (float*)(ws + 2631680);                 // 1,326,080 B
    float* covf  = (float*)(ws + 3957760);                 // 5*512*512*4 = 5,242,880 B
    // x2c aliases head of Abf (covmfma reads x2c before qtrans writes Abf)
    u16* x2c     = (u16*)(ws + 9200640);                   // 11,304,960 B
    u16* Abf     = (u16*)(ws + 9200640);                   // 66304*512*2 = 67,895,296 B

    wmean_kernel<<<WAYN * CN, 64, 0, stream>>>(x2, wmean);
    x2center_kernel<<<WAYN * SHOTN * CN, 64, 0, stream>>>(x2, wmean, x2c);
    init2_kernel<<<256, 256, 0, stream>>>(simws, covf, (u32*)(Abf + (size_t)MROWS * CN));
    covmfma_kernel<<<dim3(4, 4, WAYN * 3), 256, 0, stream>>>(x2c, covf);
    cov2b_kernel<<<WAYN * CN * CN / 256, 256, 0, stream>>>(covf, covb);
    qtrans_kernel<<<dim3(8, QN), 256, 0, stream>>>(x1, Abf);
    gemm256_kernel<<<8 * 330, 512, 131072, stream>>>(Abf, covb, simws);
    finish_kernel<<<dim3(QN, WAYN), 128, 0, stream>>>(simws, conv_w, conv_b, scores);
}